// Round 1
// baseline (494.319 us; speedup 1.0000x reference)
//
#include <hip/hip_runtime.h>
#include <math.h>

// Problem constants (fixed by reference):
//   x: [B=32, C=512, H=64, W=64] fp32; HW = 4096
//   fc1_w: [64, 768], fc1_b: [64], fc2_w: [1,64], fc2_b: [1]
// Algebraic collapse:
//   r_i[b,c,j]        = xc[b,c] * xc[b, j % 512]
//   r_i_pooled[b,c,p] = xc[b,c] * q[b, p % 128],  q[b,m] = mean(xc[b,4m..4m+3])
//   s[b,c,h] = relu(T1[b,h] + xc[b,c]*T2[b,h] + fc1_b[h])
//   a[b,c]   = sigmoid(fc2_b + sum_h fc2_w[h]*s[b,c,h])
//   out      = x * a[b,c]

#define B_  32
#define C_  512
#define HW_ 4096
#define ROWS_ (B_ * C_)   // 16384

// ---------------- Kernel 1: per-(b,c) spatial mean ----------------
__global__ __launch_bounds__(256) void k_rowmean(const float* __restrict__ x,
                                                 float* __restrict__ xc) {
    const int row = blockIdx.x;
    const float4* xr = (const float4*)(x + (size_t)row * HW_);
    const int tid = threadIdx.x;
    float s = 0.f;
#pragma unroll
    for (int k = 0; k < 4; ++k) {
        float4 v = xr[tid + k * 256];
        s += (v.x + v.y) + (v.z + v.w);
    }
    // wave(64) butterfly reduce
#pragma unroll
    for (int off = 32; off > 0; off >>= 1) s += __shfl_down(s, off, 64);
    __shared__ float wsum[4];
    const int lane = tid & 63, wave = tid >> 6;
    if (lane == 0) wsum[wave] = s;
    __syncthreads();
    if (tid == 0) {
        float t = (wsum[0] + wsum[1]) + (wsum[2] + wsum[3]);
        xc[row] = t * (1.0f / (float)HW_);
    }
}

// ---------------- Kernel 2: attention scalars a[b,c] ----------------
__global__ __launch_bounds__(256) void k_att(const float* __restrict__ xc,
                                             const float* __restrict__ fc1w,
                                             const float* __restrict__ fc1b,
                                             const float* __restrict__ fc2w,
                                             const float* __restrict__ fc2b,
                                             float* __restrict__ a) {
    const int b = blockIdx.x;       // one block per batch
    const int tid = threadIdx.x;    // 256 threads
    __shared__ float xcs[C_];
    __shared__ float qs[128];
    __shared__ float p1[256], p2[256];
    __shared__ float s1[64], s2[64], w2s[64];

    // load xc row (512 floats)
    xcs[tid]       = xc[b * C_ + tid];
    xcs[tid + 256] = xc[b * C_ + 256 + tid];
    if (tid < 64) w2s[tid] = fc2w[tid];
    __syncthreads();

    // q[m] = mean of 4 consecutive xc
    if (tid < 128) {
        qs[tid] = (xcs[4 * tid] + xcs[4 * tid + 1] + xcs[4 * tid + 2] + xcs[4 * tid + 3]) * 0.25f;
    }
    __syncthreads();

    // T1[h], T2[h]: 4 partial threads per h
    const int h = tid & 63, part = tid >> 6;
    const float* w = fc1w + h * 768;
    float t1 = 0.f, t2 = 0.f;
    {
        const int f0 = part * 128;
#pragma unroll 8
        for (int f = 0; f < 128; ++f) t1 += xcs[f0 + f] * w[f0 + f];
        const int m0 = part * 32;
#pragma unroll 8
        for (int m = 0; m < 32; ++m) t2 += qs[m0 + m] * (w[512 + m0 + m] + w[640 + m0 + m]);
    }
    p1[tid] = t1;
    p2[tid] = t2;
    __syncthreads();
    if (tid < 64) {
        s1[tid] = (p1[tid] + p1[tid + 64]) + (p1[tid + 128] + p1[tid + 192]) + fc1b[tid];
        s2[tid] = (p2[tid] + p2[tid + 64]) + (p2[tid + 128] + p2[tid + 192]);
    }
    __syncthreads();

    const float bias2 = fc2b[0];
    for (int c = tid; c < C_; c += 256) {
        const float xv = xcs[c];
        float acc = bias2;
#pragma unroll 8
        for (int hh = 0; hh < 64; ++hh) {
            float z = s1[hh] + xv * s2[hh];
            acc += w2s[hh] * (z > 0.f ? z : 0.f);
        }
        a[b * C_ + c] = 1.0f / (1.0f + __expf(-acc));
    }
}

// ---------------- Kernel 3: out = x * a[row] ----------------
__global__ __launch_bounds__(256) void k_scale(const float* __restrict__ x,
                                               const float* __restrict__ a,
                                               float* __restrict__ out) {
    const int row = blockIdx.x;
    const float s = a[row];  // block-uniform -> scalar load
    const float4* xr = (const float4*)(x + (size_t)row * HW_);
    float4* outr = (float4*)(out + (size_t)row * HW_);
    const int tid = threadIdx.x;
#pragma unroll
    for (int k = 0; k < 4; ++k) {
        float4 v = xr[tid + k * 256];
        v.x *= s; v.y *= s; v.z *= s; v.w *= s;
        outr[tid + k * 256] = v;
    }
}

extern "C" void kernel_launch(void* const* d_in, const int* in_sizes, int n_in,
                              void* d_out, int out_size, void* d_ws, size_t ws_size,
                              hipStream_t stream) {
    const float* x     = (const float*)d_in[0];
    const float* fc1_w = (const float*)d_in[1];
    const float* fc1_b = (const float*)d_in[2];
    const float* fc2_w = (const float*)d_in[3];
    const float* fc2_b = (const float*)d_in[4];
    float* out = (float*)d_out;

    float* xc = (float*)d_ws;          // ROWS_ floats
    float* a  = xc + ROWS_;            // ROWS_ floats

    k_rowmean<<<ROWS_, 256, 0, stream>>>(x, xc);
    k_att<<<B_, 256, 0, stream>>>(xc, fc1_w, fc1_b, fc2_w, fc2_b, a);
    k_scale<<<ROWS_, 256, 0, stream>>>(x, a, out);
}